// Round 3
// baseline (251.006 us; speedup 1.0000x reference)
//
#include <hip/hip_runtime.h>

// LengthRegulator fused: B=32, T=512, C=384, MAX_LEN=4096 (fixed shapes).
// out[b,p,:] = x[b, t(p), :], t(p) = #{j : csum[b,j] <= p} (clip T-1),
// zero for p >= mel_len[b] = csum[b,T-1]; mel_len appended as float32.
//
// R3 = R2 PROBE RESUBMIT (R2 failed on broker infra, no data).
// R0 fused kernel + a second identical store pass (memory-clobber fenced so
// neither pass is eliminated). Doubles stores 192->384 MiB to measure the
// effective store rate of this kernel's path:
//   dur +~29us  -> stores run at fill rate (6.6 TB/s), kernel near floor;
//                  next round: revert to R0, declare roofline.
//   dur +~95us  -> stores run at ~2 TB/s, store-path problem confirmed;
//                  kernel will also appear in rocprof top-5 with counters.
// Split-kernel variant (R1) measured +7us vs fused -> reverted to fused.

#define B   32
#define T   512
#define C4  96          // C/4 = 384/4
#define ML  4096
#define PPB 128         // positions per block
#define TPB 384         // threads per block (6 waves)

typedef float v4f __attribute__((ext_vector_type(4)));

__global__ __launch_bounds__(TPB)
void lr_fused_kernel(const float* __restrict__ x,
                     const int* __restrict__ dur,
                     float* __restrict__ out,
                     float* __restrict__ mel_out) {
    __shared__ int s_cs[T];
    __shared__ int s_wsum[4];
    __shared__ int s_idx[PPB];

    const int b     = blockIdx.x >> 5;        // / (ML/PPB) = /32
    const int ptile = blockIdx.x & 31;
    const int tid   = threadIdx.x;
    const int lane  = tid & 63;

    // ---- scan: threads 0..255 hold 2 durations each; shuffle scan ----
    int pairsum = 0, d1 = 0;
    if (tid < 256) {
        int2 d2 = ((const int2*)(dur + b * T))[tid];
        int d0 = d2.x < 0 ? 0 : d2.x;
        d1     = d2.y < 0 ? 0 : d2.y;
        pairsum = d0 + d1;
    }
    int incl = pairsum;                        // intra-wave inclusive scan
    #pragma unroll
    for (int off = 1; off < 64; off <<= 1) {
        int n = __shfl_up(incl, off, 64);
        if (lane >= off) incl += n;
    }
    if (tid < 256 && lane == 63) s_wsum[tid >> 6] = incl;
    __syncthreads();
    if (tid < 256) {
        const int w = tid >> 6;
        int wp = 0;
        #pragma unroll
        for (int j = 0; j < 3; ++j) if (j < w) wp += s_wsum[j];
        const int S = incl + wp;               // inclusive csum through 2*tid+1
        s_cs[2 * tid + 1] = S;
        s_cs[2 * tid]     = S - d1;
    }
    __syncthreads();

    const int mel = s_cs[T - 1];
    if (ptile == 0 && tid == 0) mel_out[b] = (float)mel;

    // ---- one binary search per position in this tile ----
    if (tid < PPB) {
        const int p = ptile * PPB + tid;
        int r = -1;                            // -1 => zero-fill
        if (p < mel) {
            int lo = 0, hi = T;                // first index with cs[i] > p
            while (lo < hi) {
                int mid = (lo + hi) >> 1;
                if (s_cs[mid] <= p) lo = mid + 1; else hi = mid;
            }
            r = lo < (T - 1) ? lo : (T - 1);
        }
        s_idx[tid] = r;
    }
    __syncthreads();

    // ---- streaming copy: fixed column per thread, 32 iterations ----
    const v4f* __restrict__ x4 = (const v4f*)x;
    v4f* __restrict__ o4 = (v4f*)out;
    const int sub = tid / 96;                  // 0..3 (computed once)
    const int c4  = tid - sub * 96;            // fixed float4 column
    const size_t xbase = (size_t)b * T * C4 + c4;
    const size_t obase = (size_t)b * ML * C4 + (size_t)ptile * PPB * C4 + c4;
    const v4f zero = (v4f){0.f, 0.f, 0.f, 0.f};

    #pragma unroll 8
    for (int k = 0; k < PPB / 4; ++k) {
        const int pl = 4 * k + sub;
        const int t  = s_idx[pl];
        v4f val = zero;
        if (t >= 0) val = x4[xbase + (size_t)t * C4];
        o4[obase + (size_t)pl * C4] = val;
    }

    // ---- PROBE: second identical store pass (fenced against DSE) ----
    asm volatile("" ::: "memory");

    #pragma unroll 8
    for (int k = 0; k < PPB / 4; ++k) {
        const int pl = 4 * k + sub;
        const int t  = s_idx[pl];
        v4f val = zero;
        if (t >= 0) val = x4[xbase + (size_t)t * C4];
        o4[obase + (size_t)pl * C4] = val;
    }
}

extern "C" void kernel_launch(void* const* d_in, const int* in_sizes, int n_in,
                              void* d_out, int out_size, void* d_ws, size_t ws_size,
                              hipStream_t stream) {
    const float* x   = (const float*)d_in[0];
    const int*   dur = (const int*)d_in[1];
    // d_in[2] = max_len (fixed 4096 for this bench)

    float* out     = (float*)d_out;            // B*ML*C floats
    float* mel_out = out + (size_t)B * ML * C4 * 4;  // 32 floats (tail)

    const int grid = B * (ML / PPB);           // 1024 blocks
    lr_fused_kernel<<<grid, TPB, 0, stream>>>(x, dur, out, mel_out);
}

// Round 4
// 225.917 us; speedup vs baseline: 1.1111x; 1.1111x over previous
//
#include <hip/hip_runtime.h>

// LengthRegulator fused: B=32, T=512, C=384, MAX_LEN=4096 (fixed shapes).
// out[b,p,:] = x[b, t(p), :], t(p) = #{j : csum[b,j] <= p} (clip T-1),
// zero for p >= mel_len[b] = csum[b,T-1]; mel_len appended as float32.
//
// R4 = revert to R0 (best verified, 227.2 us). Probe history:
//  - R1 split setup/stream kernels: +7 us -> prologue redundancy theory
//    falsified; fused prologue overlaps with other blocks' streaming.
//  - R3 double-store probe: +23.8 us for +192 MiB stores (~8 TB/s marginal,
//    L3-absorbed) -> store path faster than HBM drain; kernel ~40 us vs
//    ~33 us traffic floor (192 MiB store + 24 MiB gather @ 6.6 TB/s).
//  - NT stores: +11 us (earlier session) -> plain cached stores kept.
// Remaining dur_us (~185 us) is harness re-poison (768 MiB fill @ 84% peak
// HBM + memset train) — outside kernel control. This is the roofline.
//
// TPB=384 = 4*96: each thread owns a fixed float4-column c4 = tid%96 and
// row-subslot sub = tid/96 -> inner loop has no div/mod, fully coalesced.

#define B   32
#define T   512
#define C4  96          // C/4 = 384/4
#define ML  4096
#define PPB 128         // positions per block
#define TPB 384         // threads per block (6 waves)

typedef float v4f __attribute__((ext_vector_type(4)));

__global__ __launch_bounds__(TPB)
void lr_fused_kernel(const float* __restrict__ x,
                     const int* __restrict__ dur,
                     float* __restrict__ out,
                     float* __restrict__ mel_out) {
    __shared__ int s_cs[T];
    __shared__ int s_wsum[4];
    __shared__ int s_idx[PPB];

    const int b     = blockIdx.x >> 5;        // / (ML/PPB) = /32
    const int ptile = blockIdx.x & 31;
    const int tid   = threadIdx.x;
    const int lane  = tid & 63;

    // ---- scan: threads 0..255 hold 2 durations each; shuffle scan ----
    int pairsum = 0, d1 = 0;
    if (tid < 256) {
        int2 d2 = ((const int2*)(dur + b * T))[tid];
        int d0 = d2.x < 0 ? 0 : d2.x;
        d1     = d2.y < 0 ? 0 : d2.y;
        pairsum = d0 + d1;
    }
    int incl = pairsum;                        // intra-wave inclusive scan
    #pragma unroll
    for (int off = 1; off < 64; off <<= 1) {
        int n = __shfl_up(incl, off, 64);
        if (lane >= off) incl += n;
    }
    if (tid < 256 && lane == 63) s_wsum[tid >> 6] = incl;
    __syncthreads();
    if (tid < 256) {
        const int w = tid >> 6;
        int wp = 0;
        #pragma unroll
        for (int j = 0; j < 3; ++j) if (j < w) wp += s_wsum[j];
        const int S = incl + wp;               // inclusive csum through 2*tid+1
        s_cs[2 * tid + 1] = S;
        s_cs[2 * tid]     = S - d1;
    }
    __syncthreads();

    const int mel = s_cs[T - 1];
    if (ptile == 0 && tid == 0) mel_out[b] = (float)mel;

    // ---- one binary search per position in this tile ----
    if (tid < PPB) {
        const int p = ptile * PPB + tid;
        int r = -1;                            // -1 => zero-fill
        if (p < mel) {
            int lo = 0, hi = T;                // first index with cs[i] > p
            while (lo < hi) {
                int mid = (lo + hi) >> 1;
                if (s_cs[mid] <= p) lo = mid + 1; else hi = mid;
            }
            r = lo < (T - 1) ? lo : (T - 1);
        }
        s_idx[tid] = r;
    }
    __syncthreads();

    // ---- streaming copy: fixed column per thread, 32 iterations ----
    const v4f* __restrict__ x4 = (const v4f*)x;
    v4f* __restrict__ o4 = (v4f*)out;
    const int sub = tid / 96;                  // 0..3 (computed once)
    const int c4  = tid - sub * 96;            // fixed float4 column
    const size_t xbase = (size_t)b * T * C4 + c4;
    const size_t obase = (size_t)b * ML * C4 + (size_t)ptile * PPB * C4 + c4;
    const v4f zero = (v4f){0.f, 0.f, 0.f, 0.f};

    #pragma unroll 8
    for (int k = 0; k < PPB / 4; ++k) {
        const int pl = 4 * k + sub;
        const int t  = s_idx[pl];
        v4f val = zero;
        if (t >= 0) val = x4[xbase + (size_t)t * C4];
        o4[obase + (size_t)pl * C4] = val;
    }
}

extern "C" void kernel_launch(void* const* d_in, const int* in_sizes, int n_in,
                              void* d_out, int out_size, void* d_ws, size_t ws_size,
                              hipStream_t stream) {
    const float* x   = (const float*)d_in[0];
    const int*   dur = (const int*)d_in[1];
    // d_in[2] = max_len (fixed 4096 for this bench)

    float* out     = (float*)d_out;            // B*ML*C floats
    float* mel_out = out + (size_t)B * ML * C4 * 4;  // 32 floats (tail)

    const int grid = B * (ML / PPB);           // 1024 blocks
    lr_fused_kernel<<<grid, TPB, 0, stream>>>(x, dur, out, mel_out);
}